// Round 9
// baseline (922.932 us; speedup 1.0000x reference)
//
#include <hip/hip_runtime.h>

// Problem constants
#define HH 22
#define WW 22
#define HWN 484
#define NBATCH 64
#define SDIM 8
#define NMAPS (NBATCH*HWN)      // 30976
#define PADW 24
#define CELLS 576               // 24x24 padded tile
#define PADSZ (PADW*PADW)
#define INVC (1.f/14992384.f)   // 1/(NMAPS*HWN)
#define PW PADW

// 9-tap neighborhood from a contiguous padded tile
#define LD9(A, idx) \
  float x0=(A)[(idx)-PW-1], x1=(A)[(idx)-PW], x2=(A)[(idx)-PW+1], \
        x3=(A)[(idx)-1],    x4=(A)[(idx)],    x5=(A)[(idx)+1], \
        x6=(A)[(idx)+PW-1], x7=(A)[(idx)+PW], x8=(A)[(idx)+PW+1]
#define DOT9W(w9, init) \
  fmaf((w9)[0],x0,fmaf((w9)[1],x1,fmaf((w9)[2],x2,fmaf((w9)[3],x3,fmaf((w9)[4],x4, \
  fmaf((w9)[5],x5,fmaf((w9)[6],x6,fmaf((w9)[7],x7,fmaf((w9)[8],x8,(init))))))))))

#define LOAD_NB(arr, bb) do { \
    nb[0]=(arr)[(bb)-PADW-1]; nb[1]=(arr)[(bb)-PADW]; nb[2]=(arr)[(bb)-PADW+1]; \
    nb[3]=(arr)[(bb)-1];      nb[4]=(arr)[(bb)];      nb[5]=(arr)[(bb)+1]; \
    nb[6]=(arr)[(bb)+PADW-1]; nb[7]=(arr)[(bb)+PADW]; nb[8]=(arr)[(bb)+PADW+1]; } while(0)

// -------------------------------------------------- conv(1->8) stats pass (R5, proven)
__global__ __launch_bounds__(576) void k_stats(const float* __restrict__ src,
    const float* __restrict__ w, const float* __restrict__ b,
    float* __restrict__ Sg, float* __restrict__ Qg)
{
    __shared__ float xin[2][CELLS];
    __shared__ float red[16];
    int tid=threadIdx.x;
    int i=tid/PADW, j=tid-i*PADW;
    bool inter = (i>=1 && i<=22 && j>=1 && j<=22);
    int p=(i-1)*22+(j-1);
    xin[0][tid]=0.f; xin[1][tid]=0.f;
    float accS[8], accQ[8];
#pragma unroll
    for(int c=0;c<8;++c){ accS[c]=0.f; accQ[c]=0.f; }
    int m0=blockIdx.x*16;
    if(inter) xin[0][tid]=src[(size_t)m0*HWN+p];
    __syncthreads();
    for(int mi=0;mi<16;++mi){
        int cur=mi&1;
        float nx=0.f;
        if(mi<15 && inter) nx=src[(size_t)(m0+mi+1)*HWN+p];
        if(inter){
            LD9(xin[cur], tid);
#pragma unroll
            for(int c=0;c<8;++c){
                float y=DOT9W(w+c*9, b[c]);
                accS[c]+=y; accQ[c]=fmaf(y,y,accQ[c]);
            }
        }
        if(mi<15 && inter) xin[cur^1][tid]=nx;
        __syncthreads();
    }
    if(tid<16) red[tid]=0.f;
    __syncthreads();
#pragma unroll
    for(int c=0;c<8;++c){
        float s=accS[c], q=accQ[c];
        for(int o=32;o;o>>=1){ s+=__shfl_down(s,o); q+=__shfl_down(q,o); }
        if((tid&63)==0){ atomicAdd(&red[c],s); atomicAdd(&red[8+c],q); }
    }
    __syncthreads();
    if(tid<8){ atomicAdd(&Sg[tid],red[tid]); atomicAdd(&Qg[tid],red[8+tid]); }
}

// ------ conv(1->8)+BN(in-block finalize)+ReLU+conv(8->1), out stats (R5, proven)
__global__ __launch_bounds__(576) void k_convpair(const float* __restrict__ src, float* __restrict__ Ydst,
    const float* __restrict__ w1, const float* __restrict__ b1,
    const float* __restrict__ Sin, const float* __restrict__ Qin,
    const float* __restrict__ g, const float* __restrict__ be,
    const float* __restrict__ w2, const float* __restrict__ b2,
    float* __restrict__ Sg, float* __restrict__ Qg)
{
    __shared__ float xin[2][CELLS];
    __shared__ float z[8][CELLS];
    __shared__ float scs[8], shs[8];
    __shared__ float red[2];
    int tid=threadIdx.x;
    int i=tid/PADW, j=tid-i*PADW;
    bool inter = (i>=1 && i<=22 && j>=1 && j<=22);
    int p=(i-1)*22+(j-1);
    xin[0][tid]=0.f; xin[1][tid]=0.f;
#pragma unroll
    for(int c=0;c<8;++c) z[c][tid]=0.f;      // pad cells stay zero forever
    if(tid<8){
        float mean=Sin[tid]*INVC;
        float var=fmaf(-mean,mean,Qin[tid]*INVC);
        float sc=g[tid]*rsqrtf(var+1e-5f);
        scs[tid]=sc; shs[tid]=fmaf(-mean,sc,be[tid]);
    }
    float aS=0.f, aQ=0.f;
    float b2v=b2[0];
    int m0=blockIdx.x*16;
    if(inter) xin[0][tid]=src[(size_t)m0*HWN+p];
    __syncthreads();
    for(int mi=0;mi<16;++mi){
        int cur=mi&1;
        float nx=0.f;
        if(mi<15 && inter) nx=src[(size_t)(m0+mi+1)*HWN+p];
        if(inter){
            LD9(xin[cur], tid);
#pragma unroll
            for(int c=0;c<8;++c){
                float y=DOT9W(w1+c*9, b1[c]);
                y=fmaf(y,scs[c],shs[c]);
                z[c][tid]=y>0.f?y:0.f;
            }
        }
        if(mi<15 && inter) xin[cur^1][tid]=nx;
        __syncthreads();                 // z ready (stage for m+1 also done)
        if(inter){
            float y=b2v;
#pragma unroll
            for(int c=0;c<8;++c){
                LD9(z[c], tid);
                y=DOT9W(w2+c*9, y);
            }
            Ydst[(size_t)(m0+mi)*HWN+p]=y;
            aS+=y; aQ=fmaf(y,y,aQ);
        }
        __syncthreads();                 // protect z before next conv1
    }
    if(tid<2) red[tid]=0.f;
    __syncthreads();
    for(int o=32;o;o>>=1){ aS+=__shfl_down(aS,o); aQ+=__shfl_down(aQ,o); }
    if((tid&63)==0){ atomicAdd(&red[0],aS); atomicAdd(&red[1],aQ); }
    __syncthreads();
    if(tid==0){ atomicAdd(Sg,red[0]); atomicAdd(Qg,red[1]); }
}

// ---- BN affine + per-map softmax (in place on Y) fused with conv(1->8) stats (R5, proven)
__global__ __launch_bounds__(576) void k_smax_stats(float* __restrict__ Y,
    const float* __restrict__ S2, const float* __restrict__ Q2,
    const float* __restrict__ g2, const float* __restrict__ be2,
    const float* __restrict__ w, const float* __restrict__ b,
    float* __restrict__ Sg, float* __restrict__ Qg)
{
    __shared__ float xin[CELLS];
    __shared__ float red9[9];
    __shared__ float red[16];
    int tid=threadIdx.x;
    int i=tid/PADW, j=tid-i*PADW;
    bool inter = (i>=1 && i<=22 && j>=1 && j<=22);
    int p=(i-1)*22+(j-1);
    float mean=S2[0]*INVC;
    float var=fmaf(-mean,mean,Q2[0]*INVC);
    float a=g2[0]*rsqrtf(var+1e-5f);
    float sh=fmaf(-mean,a,be2[0]);
    xin[tid]=0.f;
    float accS[8], accQ[8];
#pragma unroll
    for(int c=0;c<8;++c){ accS[c]=0.f; accQ[c]=0.f; }
    int m0=blockIdx.x*16;
    for(int mi=0;mi<16;++mi){
        size_t off=(size_t)(m0+mi)*HWN+p;
        // exp without max-shift: BN-normalized input, fp32-safe (validated R5-R7)
        float e = inter ? __expf(fmaf(Y[off],a,sh)) : 0.f;
        float part=e;
        for(int o=32;o;o>>=1) part+=__shfl_down(part,o);
        if((tid&63)==0) red9[tid>>6]=part;
        xin[tid]=e;                       // pad lanes write 0
        __syncthreads();
        float sum=red9[0]+red9[1]+red9[2]+red9[3]+red9[4]+red9[5]+red9[6]+red9[7]+red9[8];
        float inv=1.f/sum;
        if(inter){
            Y[off]=e*inv;
            LD9(xin, tid);                // raw exp values; fold inv into dot
#pragma unroll
            for(int c=0;c<8;++c){
                float d=DOT9W(w+c*9, 0.f);
                float y=fmaf(inv,d,b[c]);
                accS[c]+=y; accQ[c]=fmaf(y,y,accQ[c]);
            }
        }
        __syncthreads();                  // protect xin & red9
    }
    if(tid<16) red[tid]=0.f;
    __syncthreads();
#pragma unroll
    for(int c=0;c<8;++c){
        float s=accS[c], q=accQ[c];
        for(int o=32;o;o>>=1){ s+=__shfl_down(s,o); q+=__shfl_down(q,o); }
        if((tid&63)==0){ atomicAdd(&red[c],s); atomicAdd(&red[8+c],q); }
    }
    __syncthreads();
    if(tid<8){ atomicAdd(&Sg[tid],red[tid]); atomicAdd(&Qg[tid],red[8+tid]); }
}

// -------- column softmax over p + conf + einsum, 4-way p-split (R6/R7, proven)
__global__ __launch_bounds__(512) void k_prop(const float* __restrict__ Y,
    const float* __restrict__ S4, const float* __restrict__ Q4,
    const float* __restrict__ g4, const float* __restrict__ be4,
    const float* __restrict__ state, float* __restrict__ prop, float* __restrict__ conf)
{
    int n=blockIdx.x;
    __shared__ float sst[8*HWN];
    __shared__ float part[4][121][10];
    int tid=threadIdx.x;
    for(int q=tid;q<8*HWN;q+=512) sst[q]=state[(size_t)n*8*HWN + q];
    __syncthreads();
    int tq=tid&127, pc=tid>>7;
    int t=blockIdx.y*121+tq;
    float mean=S4[0]*INVC;
    float var=fmaf(-mean,mean,Q4[0]*INVC);
    float a=g4[0]*rsqrtf(var+1e-5f);
    float sh=fmaf(-mean,a,be4[0]);
    if(tq<121){
        const float* col = Y + (size_t)n*HWN*HWN + t + (size_t)pc*121*HWN;
        const float* sp = sst + pc*121;
        float mx=-1e30f, ssum=0.f;
        float acc[8];
#pragma unroll
        for(int d=0;d<8;++d) acc[d]=0.f;
#pragma unroll 4
        for(int p=0;p<121;++p){
            float v=fmaf(col[(size_t)p*HWN], a, sh);
            float e=__expf(v);
            mx=fmaxf(mx,v); ssum+=e;
#pragma unroll
            for(int d=0;d<8;++d) acc[d]=fmaf(e, sp[d*HWN+p], acc[d]);
        }
        part[pc][tq][0]=ssum; part[pc][tq][1]=mx;
#pragma unroll
        for(int d=0;d<8;++d) part[pc][tq][2+d]=acc[d];
    }
    __syncthreads();
    if(pc==0 && tq<121){
        float ssum=part[0][tq][0]+part[1][tq][0]+part[2][tq][0]+part[3][tq][0];
        float mx=fmaxf(fmaxf(part[0][tq][1],part[1][tq][1]),fmaxf(part[2][tq][1],part[3][tq][1]));
        float inv=1.f/ssum;
        conf[(size_t)n*HWN+t]=__expf(mx)*inv;
#pragma unroll
        for(int d=0;d<8;++d){
            float acd=part[0][tq][2+d]+part[1][tq][2+d]+part[2][tq][2+d]+part[3][tq][2+d];
            prop[((size_t)n*8+d)*HWN+t]=acd*inv;
        }
    }
}

// ------------------------------------------------ response conv1: 10 -> 64
__global__ __launch_bounds__(256) void k_rp1(const float* __restrict__ prop,
    const float* __restrict__ dimp, const float* __restrict__ conf,
    const float* __restrict__ wf, const float* __restrict__ bfv, float* __restrict__ R1)
{
    int n=blockIdx.x, g=blockIdx.y;
    __shared__ float pin[10*PADSZ];
    int tid=threadIdx.x;
    for(int i=tid;i<10*PADSZ;i+=256) pin[i]=0.f;
    __syncthreads();
    for(int p=tid;p<HWN;p+=256){
        int i=p/WW, j=p-i*WW; int aa=(i+1)*PADW+j+1;
#pragma unroll
        for(int d=0;d<8;++d) pin[d*PADSZ+aa]=prop[((size_t)n*8+d)*HWN+p];
        pin[8*PADSZ+aa]=dimp[(size_t)n*HWN+p];
        pin[9*PADSZ+aa]=conf[(size_t)n*HWN+p];
    }
    __syncthreads();
    const float* wg = wf + (size_t)(g*16)*90;
    for(int p=tid;p<HWN;p+=256){
        int i=p/WW, j=p-i*WW; int aa=(i+1)*PADW+j+1;
        float acc[16];
#pragma unroll
        for(int o=0;o<16;++o) acc[o]=bfv[g*16+o];
#pragma unroll
        for(int c=0;c<10;++c){
            float nb[9]; int bb=c*PADSZ+aa;
            LOAD_NB(pin, bb);
#pragma unroll
            for(int o=0;o<16;++o){
                const float* w=wg+o*90+c*9;
#pragma unroll
                for(int t=0;t<9;++t) acc[o]=fmaf(w[t], nb[t], acc[o]);
            }
        }
#pragma unroll
        for(int o=0;o<16;++o){
            float y=acc[o];
            R1[((size_t)n*64 + g*16+o)*HWN+p]= y>0.f?y:0.f;
        }
    }
}

// ------------------------------------------------ response conv2: 64 -> 32
__global__ __launch_bounds__(512) void k_rp2(const float* __restrict__ R1,
    const float* __restrict__ wf, const float* __restrict__ bfv, float* __restrict__ R2)
{
    int n=blockIdx.x, g=blockIdx.y;
    __shared__ float xc[16*PADSZ];
    int tid=threadIdx.x;
    for(int i=tid;i<16*PADSZ;i+=512) xc[i]=0.f;
    int p=tid; bool act = p<HWN;
    int i=p/WW, j=p-i*WW, aa=(i+1)*PADW+j+1;
    float acc[8];
#pragma unroll
    for(int o=0;o<8;++o) acc[o]=0.f;
    for(int k=0;k<4;++k){
        __syncthreads();
        for(int q=tid;q<16*HWN;q+=512){
            int ic=q/HWN, pp=q-ic*HWN;
            int ii=pp/WW, jj=pp-ii*WW;
            xc[ic*PADSZ+(ii+1)*PADW+jj+1]=R1[((size_t)n*64 + k*16+ic)*HWN+pp];
        }
        __syncthreads();
        if(act){
#pragma unroll
            for(int ic=0;ic<16;++ic){
                float nb[9]; int bb=ic*PADSZ+aa;
                LOAD_NB(xc, bb);
#pragma unroll
                for(int o=0;o<8;++o){
                    const float* w = wf + ((size_t)(g*8+o)*64 + k*16+ic)*9;
#pragma unroll
                    for(int t=0;t<9;++t) acc[o]=fmaf(w[t], nb[t], acc[o]);
                }
            }
        }
    }
    if(act){
#pragma unroll
        for(int o=0;o<8;++o){
            float y=acc[o]+bfv[g*8+o];
            R2[((size_t)n*32+g*8+o)*HWN+p]= y>0.f?y:0.f;
        }
    }
}

// ------------------- response conv3: 32 -> 1, sigmoid, + per-n max pools
__global__ __launch_bounds__(512) void k_resp(const float* __restrict__ R2,
    const float* __restrict__ wf, const float* __restrict__ bfv,
    const float* __restrict__ dimp, float* __restrict__ fused,
    float* __restrict__ pool, float* __restrict__ out)
{
    int n=blockIdx.x;
    __shared__ float xc[16*PADSZ];
    __shared__ float redf[8], redd[8];
    int tid=threadIdx.x;
    for(int i=tid;i<16*PADSZ;i+=512) xc[i]=0.f;
    int p=tid; bool act=p<HWN;
    int i=p/WW, j=p-i*WW, aa=(i+1)*PADW+j+1;
    float acc=0.f;
    for(int k=0;k<2;++k){
        __syncthreads();
        for(int q=tid;q<16*HWN;q+=512){
            int ic=q/HWN, pp=q-ic*HWN;
            int ii=pp/WW, jj=pp-ii*WW;
            xc[ic*PADSZ+(ii+1)*PADW+jj+1]=R2[((size_t)n*32+k*16+ic)*HWN+pp];
        }
        __syncthreads();
        if(act){
#pragma unroll
            for(int ic=0;ic<16;++ic){
                float nb[9]; int bb=ic*PADSZ+aa;
                LOAD_NB(xc, bb);
                const float* w=wf+(size_t)(k*16+ic)*9;
#pragma unroll
                for(int t=0;t<9;++t) acc=fmaf(w[t], nb[t], acc);
            }
        }
    }
    float fval=-1e30f, dval=-1e30f;
    if(act){
        float y=acc+bfv[0];
        float s=1.f/(1.f+__expf(-y));
        fused[(size_t)n*HWN+p]=s;
        out[(size_t)n*9*HWN+p]=s;
        fval=s;
        dval=dimp[(size_t)n*HWN+p];
    }
    int lane=tid&63, wid=tid>>6;
    for(int o=32;o;o>>=1){ fval=fmaxf(fval,__shfl_xor(fval,o)); dval=fmaxf(dval,__shfl_xor(dval,o)); }
    if(lane==0){ redf[wid]=fval; redd[wid]=dval; }
    __syncthreads();
    if(tid==0){
        float fm=redf[0], dm=redd[0];
        for(int q=1;q<8;++q){ fm=fmaxf(fm,redf[q]); dm=fmaxf(dm,redd[q]); }
        pool[n*2+0]=dm; pool[n*2+1]=fm;
    }
}

// --------------------------------------------------------------- ConvGRU
__global__ __launch_bounds__(512) void k_gru(const float* __restrict__ dimp,
    const float* __restrict__ fused, const float* __restrict__ pool,
    const float* __restrict__ prop,
    const float* __restrict__ wr, const float* __restrict__ br,
    const float* __restrict__ wu, const float* __restrict__ bu,
    const float* __restrict__ wo, const float* __restrict__ bo,
    float* __restrict__ out)
{
    int n=blockIdx.x;
    __shared__ float sg[12*PADSZ];
    __shared__ float pr[8*PADSZ];
    int tid=threadIdx.x;
    for(int i=tid;i<12*PADSZ;i+=512) sg[i]=0.f;
    for(int i=tid;i<8*PADSZ;i+=512) pr[i]=0.f;
    __syncthreads();
    float p0=pool[n*2+0], p1=pool[n*2+1];
    for(int p=tid;p<HWN;p+=512){
        int i=p/WW, j=p-i*WW, aa=(i+1)*PADW+j+1;
        sg[0*PADSZ+aa]=dimp[(size_t)n*HWN+p];
        sg[1*PADSZ+aa]=fused[(size_t)n*HWN+p];
        sg[2*PADSZ+aa]=p0;
        sg[3*PADSZ+aa]=p1;
#pragma unroll
        for(int d=0;d<8;++d) sg[(4+d)*PADSZ+aa]=prop[((size_t)n*8+d)*HWN+p];
    }
    __syncthreads();
    int p=tid; bool act=p<HWN;
    int i=p/WW, j=p-i*WW, aa=(i+1)*PADW+j+1;
    float upd[8];
    if(act){
        float ua[8], ra[8];
#pragma unroll
        for(int o=0;o<8;++o){ ua[o]=bu[o]; ra[o]=br[o]; }
#pragma unroll
        for(int ic=0;ic<12;++ic){
            float nb[9]; int bb=ic*PADSZ+aa;
            LOAD_NB(sg, bb);
#pragma unroll
            for(int o=0;o<8;++o){
                const float* wup=wu+((size_t)o*12+ic)*9;
                const float* wrp=wr+((size_t)o*12+ic)*9;
#pragma unroll
                for(int t=0;t<9;++t){
                    ua[o]=fmaf(wup[t], nb[t], ua[o]);
                    ra[o]=fmaf(wrp[t], nb[t], ra[o]);
                }
            }
        }
#pragma unroll
        for(int o=0;o<8;++o){
            upd[o]=1.f/(1.f+__expf(-ua[o]));
            float rst=1.f/(1.f+__expf(-ra[o]));
            pr[o*PADSZ+aa]=sg[(4+o)*PADSZ+aa]*rst;
        }
    }
    __syncthreads();
    if(act){
        float oa[8];
#pragma unroll
        for(int o=0;o<8;++o) oa[o]=bo[o];
#pragma unroll
        for(int ic=0;ic<12;++ic){
            const float* srcp = (ic<4)? (sg+ic*PADSZ) : (pr+(ic-4)*PADSZ);
            float nb[9]; int bb=aa;
            LOAD_NB(srcp, bb);
#pragma unroll
            for(int o=0;o<8;++o){
                const float* wop=wo+((size_t)o*12+ic)*9;
#pragma unroll
                for(int t=0;t<9;++t) oa[o]=fmaf(wop[t], nb[t], oa[o]);
            }
        }
#pragma unroll
        for(int o=0;o<8;++o){
            float od=tanhf(oa[o]);
            float ph=sg[(4+o)*PADSZ+aa];
            float sn=ph*(1.f-upd[o])+od*upd[o];
            out[((size_t)n*9+1+o)*HWN+p]=sn;
        }
    }
}

// ===========================================================================
extern "C" void kernel_launch(void* const* d_in, const int* in_sizes, int n_in,
                              void* d_out, int out_size, void* d_ws, size_t ws_size,
                              hipStream_t stream)
{
    (void)in_sizes; (void)n_in; (void)out_size; (void)ws_size;
    float* ws=(float*)d_ws;
    float* Y     = ws;                       // 14,992,384 floats
    float* PROP  = ws + 14992384;            // 247,808
    float* CONF  = PROP + 247808;            // 30,976
    float* FUSED = CONF + 30976;             // 30,976
    float* POOL  = FUSED + 30976;            // 128
    float* STATS = POOL + 128;               // 36
    float* R1    = ws;                       // alias Y (dead after k_prop)
    float* R2    = ws + 4000000;

    const float* cv    = (const float*)d_in[0];
    const float* state = (const float*)d_in[1];
    const float* dimp  = (const float*)d_in[2];
    float* out = (float*)d_out;

    hipMemsetAsync(STATS, 0, 36*sizeof(float), stream);

    float *S1=STATS,*Q1=STATS+8,*S2=STATS+16,*Q2=STATS+17,*S3=STATS+18,*Q3=STATS+26,*S4=STATS+34,*Q4=STATS+35;

    const float* cv1_w1=(const float*)d_in[3];  const float* cv1_b1=(const float*)d_in[4];
    const float* cv1_g1=(const float*)d_in[5];  const float* cv1_be1=(const float*)d_in[6];
    const float* cv1_w2=(const float*)d_in[7];  const float* cv1_b2=(const float*)d_in[8];
    const float* cv1_g2=(const float*)d_in[9];  const float* cv1_be2=(const float*)d_in[10];
    const float* cv2_w1=(const float*)d_in[11]; const float* cv2_b1=(const float*)d_in[12];
    const float* cv2_g1=(const float*)d_in[13]; const float* cv2_be1=(const float*)d_in[14];
    const float* cv2_w2=(const float*)d_in[15]; const float* cv2_b2=(const float*)d_in[16];
    const float* cv2_g2=(const float*)d_in[17]; const float* cv2_be2=(const float*)d_in[18];
    const float* rp1_w=(const float*)d_in[19];  const float* rp1_b=(const float*)d_in[20];
    const float* rp2_w=(const float*)d_in[21];  const float* rp2_b=(const float*)d_in[22];
    const float* resp_w=(const float*)d_in[23]; const float* resp_b=(const float*)d_in[24];
    const float* gru_rw=(const float*)d_in[25]; const float* gru_rb=(const float*)d_in[26];
    const float* gru_uw=(const float*)d_in[27]; const float* gru_ub=(const float*)d_in[28];
    const float* gru_ow=(const float*)d_in[29]; const float* gru_ob=(const float*)d_in[30];

    // cv1 stack
    k_stats<<<1936,576,0,stream>>>(cv, cv1_w1, cv1_b1, S1, Q1);
    k_convpair<<<1936,576,0,stream>>>(cv, Y, cv1_w1, cv1_b1, S1, Q1, cv1_g1, cv1_be1,
                                      cv1_w2, cv1_b2, S2, Q2);
    // BN2 affine + per-map softmax + cv2 conv1 stats (fused)
    k_smax_stats<<<1936,576,0,stream>>>(Y, S2, Q2, cv1_g2, cv1_be2, cv2_w1, cv2_b1, S3, Q3);
    // cv2 stack (in place on Y)
    k_convpair<<<1936,576,0,stream>>>(Y, Y, cv2_w1, cv2_b1, S3, Q3, cv2_g1, cv2_be1,
                                      cv2_w2, cv2_b2, S4, Q4);
    // column softmax over p + conf + propagation einsum (4-way p-split)
    k_prop<<<dim3(64,4),512,0,stream>>>(Y, S4, Q4, cv2_g2, cv2_be2, state, PROP, CONF);
    // response head
    k_rp1<<<dim3(64,4),256,0,stream>>>(PROP, dimp, CONF, rp1_w, rp1_b, R1);
    k_rp2<<<dim3(64,4),512,0,stream>>>(R1, rp2_w, rp2_b, R2);
    k_resp<<<64,512,0,stream>>>(R2, resp_w, resp_b, dimp, FUSED, POOL, out);
    // ConvGRU
    k_gru<<<64,512,0,stream>>>(dimp, FUSED, POOL, PROP,
                               gru_rw, gru_rb, gru_uw, gru_ub, gru_ow, gru_ob, out);
}